// Round 1
// baseline (2927.574 us; speedup 1.0000x reference)
//
#include <hip/hip_runtime.h>
#include <math.h>

#define LSEQ   16384
#define DM     128
#define DI     256
#define DSTATE 64
#define NH     4
#define HD     64
#define CONVD  384
#define DPROJ  644
#define NDIR   6
#define NCHUNK 256      // LSEQ/64
#define PAD    66       // LDS row stride (floats): float2-aligned, low bank conflicts

__device__ __constant__ int ORD[6][3] = {{0,1,2},{0,2,1},{1,0,2},{1,2,0},{2,0,1},{2,1,0}};

__device__ __forceinline__ float softplus_f(float x){
  float ax = fabsf(x);
  return fmaxf(x, 0.f) + log1pf(__expf(-ax));
}
__device__ __forceinline__ float silu_f(float x){
  return x / (1.f + __expf(-x));
}

// ---------------- sort: bucket by primary coord, O(m^2) in-bucket rank ----------------
__global__ __launch_bounds__(256) void k_sort1(const int* __restrict__ coords,
                                               unsigned long long* __restrict__ skey,
                                               int* __restrict__ cursor){
  int i = blockIdx.x*256 + threadIdx.x;
  if (i >= NDIR*LSEQ) return;
  int d = i >> 14, t = i & 16383;
  unsigned k = ((unsigned)coords[t*4 + ORD[d][0]] << 20)
             | ((unsigned)coords[t*4 + ORD[d][1]] << 10)
             |  (unsigned)coords[t*4 + ORD[d][2]];
  skey[i] = ((unsigned long long)k << 14) | (unsigned long long)t;
  atomicAdd(&cursor[(d << 10) + (k >> 20)], 1);
}

__global__ void k_sort_scan(int* __restrict__ cursor, int* __restrict__ starts){
  __shared__ int sh[1024];
  int d = blockIdx.x, t = threadIdx.x;
  int v = cursor[d*1024 + t];
  sh[t] = v; __syncthreads();
  for (int off = 1; off < 1024; off <<= 1){
    int a = (t >= off) ? sh[t-off] : 0;
    __syncthreads();
    sh[t] += a;
    __syncthreads();
  }
  int incl = sh[t], excl = incl - v;
  starts[d*1025 + t] = excl;
  cursor[d*1024 + t] = excl;
  if (t == 1023) starts[d*1025 + 1024] = incl;
}

__global__ __launch_bounds__(256) void k_sort_scatter(const unsigned long long* __restrict__ skey,
                                                      unsigned long long* __restrict__ skey2,
                                                      int* __restrict__ cursor){
  int i = blockIdx.x*256 + threadIdx.x;
  if (i >= NDIR*LSEQ) return;
  int d = i >> 14;
  unsigned long long v = skey[i];
  int b = (int)(v >> 34);
  int pos = atomicAdd(&cursor[(d << 10) + b], 1);
  skey2[(size_t)d*LSEQ + pos] = v;
}

__global__ __launch_bounds__(256) void k_sort_rank(const unsigned long long* __restrict__ skey2,
                                                   const int* __restrict__ starts,
                                                   int* __restrict__ idx, int* __restrict__ inv){
  int i = blockIdx.x*256 + threadIdx.x;
  if (i >= NDIR*LSEQ) return;
  int d = i >> 14;
  unsigned long long v = skey2[i];
  int b = (int)(v >> 34);
  int s = starts[d*1025 + b], e = starts[d*1025 + b + 1];
  int r = s;
  for (int q = s; q < e; ++q) r += (skey2[(size_t)d*LSEQ + q] < v);
  int orig = (int)(v & 16383ULL);
  idx[(size_t)d*LSEQ + r] = orig;
  inv[(size_t)d*LSEQ + orig] = r;
}

// ---------------- gather / scatter ----------------
__global__ __launch_bounds__(256) void k_gather(const float* __restrict__ vec, const int* __restrict__ idx,
                                                float* __restrict__ x, int d_base, int nd){
  int i = blockIdx.x*256 + threadIdx.x;
  if (i >= nd*LSEQ*32) return;
  int c4 = i & 31, r = (i >> 5) & 16383, dz = i >> 19;
  int src = idx[(size_t)(d_base+dz)*LSEQ + r];
  ((float4*)x)[((size_t)dz*LSEQ + r)*32 + c4] = ((const float4*)vec)[(size_t)src*32 + c4];
}

__global__ __launch_bounds__(256) void k_scatter(const float* __restrict__ x, const int* __restrict__ idx,
                                                 float* __restrict__ multi, int d_base, int nd){
  int i = blockIdx.x*256 + threadIdx.x;
  if (i >= nd*LSEQ*32) return;
  int c4 = i & 31, r = (i >> 5) & 16383, dz = i >> 19;
  int orig = idx[(size_t)(d_base+dz)*LSEQ + r];
  ((float4*)multi)[(size_t)orig*192 + (d_base+dz)*32 + c4] =
      ((const float4*)x)[((size_t)dz*LSEQ + r)*32 + c4];
}

// ---------------- layernorms ----------------
__global__ __launch_bounds__(256) void k_ln128(const float* __restrict__ x, const float* __restrict__ w,
                                               const float* __restrict__ b, float* __restrict__ u,
                                               int d_base, int j, int nd){
  int gt = blockIdx.x*256 + threadIdx.x;
  int wid = gt >> 6, lane = gt & 63;
  if (wid >= nd*LSEQ) return;
  int dz = wid >> 14;
  int dj = (d_base+dz)*2 + j;
  float2 v = ((const float2*)(x + (size_t)wid*DM))[lane];
  float s = v.x + v.y, ss = v.x*v.x + v.y*v.y;
  #pragma unroll
  for (int o = 32; o; o >>= 1){ s += __shfl_xor(s,o); ss += __shfl_xor(ss,o); }
  float mu = s * (1.f/128.f);
  float var = ss * (1.f/128.f) - mu*mu;
  float inv = rsqrtf(var + 1e-5f);
  float2 wv = ((const float2*)(w + (size_t)dj*DM))[lane];
  float2 bv = ((const float2*)(b + (size_t)dj*DM))[lane];
  float2 o2;
  o2.x = (v.x - mu)*inv*wv.x + bv.x;
  o2.y = (v.y - mu)*inv*wv.y + bv.y;
  ((float2*)(u + (size_t)wid*DM))[lane] = o2;
}

__global__ __launch_bounds__(256) void k_ln768(const float* __restrict__ m, const float* __restrict__ w,
                                               const float* __restrict__ b, float* __restrict__ o){
  int gt = blockIdx.x*256 + threadIdx.x;
  int wid = gt >> 6, lane = gt & 63;
  if (wid >= LSEQ) return;
  const float4* row = (const float4*)(m + (size_t)wid*768);
  float4 v0 = row[lane], v1 = row[lane+64], v2 = row[lane+128];
  float s  = v0.x+v0.y+v0.z+v0.w + v1.x+v1.y+v1.z+v1.w + v2.x+v2.y+v2.z+v2.w;
  float ss = v0.x*v0.x+v0.y*v0.y+v0.z*v0.z+v0.w*v0.w
           + v1.x*v1.x+v1.y*v1.y+v1.z*v1.z+v1.w*v1.w
           + v2.x*v2.x+v2.y*v2.y+v2.z*v2.z+v2.w*v2.w;
  #pragma unroll
  for (int off = 32; off; off >>= 1){ s += __shfl_xor(s,off); ss += __shfl_xor(ss,off); }
  float mu = s * (1.f/768.f);
  float var = ss * (1.f/768.f) - mu*mu;
  float inv = rsqrtf(var + 1e-5f);
  const float4* w4 = (const float4*)w;
  const float4* b4 = (const float4*)b;
  float4* orow = (float4*)(o + (size_t)wid*768);
  #pragma unroll
  for (int kk = 0; kk < 3; ++kk){
    float4 v = (kk==0)?v0:((kk==1)?v1:v2);
    float4 W = w4[lane + kk*64], B = b4[lane + kk*64];
    float4 r;
    r.x = (v.x-mu)*inv*W.x + B.x;
    r.y = (v.y-mu)*inv*W.y + B.y;
    r.z = (v.z-mu)*inv*W.z + B.z;
    r.w = (v.w-mu)*inv*W.w + B.w;
    orow[lane + kk*64] = r;
  }
}

// ---------------- fp32 tiled GEMM helpers ----------------
__device__ __forceinline__ void stageT(const float* __restrict__ src, int ld, int nrows,
                                       float* __restrict__ dst, int tid){
  int rb = tid >> 6, k = tid & 63;
  #pragma unroll
  for (int i = 0; i < 16; ++i){
    int r = i*4 + rb;
    float v = (r < nrows) ? src[(size_t)r*ld + k] : 0.f;
    dst[k*PAD + r] = v;
  }
}

__device__ __forceinline__ void mac16(const float* __restrict__ A, const float* __restrict__ B,
                                      int m0, int n0, float acc[4][4]){
  #pragma unroll
  for (int k = 0; k < 64; ++k){
    const float* a = A + k*PAD + m0;
    const float* b = B + k*PAD + n0;
    float a0=a[0],a1=a[1],a2=a[2],a3=a[3];
    float b0=b[0],b1=b[1],b2=b[2],b3=b[3];
    acc[0][0]=fmaf(a0,b0,acc[0][0]); acc[0][1]=fmaf(a0,b1,acc[0][1]);
    acc[0][2]=fmaf(a0,b2,acc[0][2]); acc[0][3]=fmaf(a0,b3,acc[0][3]);
    acc[1][0]=fmaf(a1,b0,acc[1][0]); acc[1][1]=fmaf(a1,b1,acc[1][1]);
    acc[1][2]=fmaf(a1,b2,acc[1][2]); acc[1][3]=fmaf(a1,b3,acc[1][3]);
    acc[2][0]=fmaf(a2,b0,acc[2][0]); acc[2][1]=fmaf(a2,b1,acc[2][1]);
    acc[2][2]=fmaf(a2,b2,acc[2][2]); acc[2][3]=fmaf(a2,b3,acc[2][3]);
    acc[3][0]=fmaf(a3,b0,acc[3][0]); acc[3][1]=fmaf(a3,b1,acc[3][1]);
    acc[3][2]=fmaf(a3,b2,acc[3][2]); acc[3][3]=fmaf(a3,b3,acc[3][3]);
  }
}

// ---------------- in_proj: u[L,128] @ in_w[644,128]^T -> zx[L,644] ----------------
__global__ __launch_bounds__(256) void k_inproj(const float* __restrict__ u, const float* __restrict__ in_w,
                                                float* __restrict__ zx, int d_base, int j){
  __shared__ float As[64*PAD], Ws[64*PAD];
  int tid = threadIdx.x, mt = blockIdx.x, nt = blockIdx.y, dz = blockIdx.z;
  const float* A = u + ((size_t)dz*LSEQ + mt*64)*DM;
  const float* W = in_w + (size_t)((d_base+dz)*2 + j)*DPROJ*DM + (size_t)nt*64*DM;
  int nv = DPROJ - nt*64; if (nv > 64) nv = 64;
  float acc[4][4] = {};
  for (int kt = 0; kt < DM; kt += 64){
    stageT(A + kt, DM, 64, As, tid);
    stageT(W + kt, DM, nv, Ws, tid);
    __syncthreads();
    mac16(As, Ws, (tid>>4)*4, (tid&15)*4, acc);
    __syncthreads();
  }
  int m0 = (tid>>4)*4, n0 = (tid&15)*4;
  float* orow = zx + ((size_t)dz*LSEQ + mt*64 + m0)*DPROJ;
  #pragma unroll
  for (int r = 0; r < 4; ++r)
    #pragma unroll
    for (int c = 0; c < 4; ++c){
      int col = nt*64 + n0 + c;
      if (col < DPROJ) orow[(size_t)r*DPROJ + col] = acc[r][c];
    }
}

// ---------------- depthwise conv(4) + bias + silu ----------------
__global__ __launch_bounds__(256) void k_conv(const float* __restrict__ zx, const float* __restrict__ conv_w,
                                              const float* __restrict__ conv_b, float* __restrict__ xact,
                                              int d_base, int j){
  __shared__ float tile[67][129];
  __shared__ float wsh[128][4];
  __shared__ float bsh[128];
  int dz = blockIdx.x, lb = blockIdx.y*64, cb = blockIdx.z*128;
  int dj = (d_base+dz)*2 + j;
  const float* src = zx + (size_t)dz*LSEQ*DPROJ + 256 + cb;
  for (int e = threadIdx.x; e < 67*128; e += 256){
    int r = e >> 7, c = e & 127;
    int l = lb - 3 + r;
    tile[r][c] = (l >= 0) ? src[(size_t)l*DPROJ + c] : 0.f;
  }
  if (threadIdx.x < 128){
    int c = threadIdx.x;
    const float* wp = conv_w + ((size_t)dj*CONVD + cb + c)*4;
    wsh[c][0]=wp[0]; wsh[c][1]=wp[1]; wsh[c][2]=wp[2]; wsh[c][3]=wp[3];
    bsh[c] = conv_b[(size_t)dj*CONVD + cb + c];
  }
  __syncthreads();
  for (int e = threadIdx.x; e < 64*128; e += 256){
    int r = e >> 7, c = e & 127;
    float v = tile[r][c]*wsh[c][0] + tile[r+1][c]*wsh[c][1]
            + tile[r+2][c]*wsh[c][2] + tile[r+3][c]*wsh[c][3] + bsh[c];
    v = silu_f(v);
    xact[((size_t)dz*LSEQ + lb + r)*CONVD + cb + c] = v;
  }
}

// ---------------- dt = softplus(raw + bias) ----------------
__global__ __launch_bounds__(256) void k_dt(const float* __restrict__ zx, const float* __restrict__ dt_bias,
                                            float* __restrict__ dtb, int d_base, int j, int nd){
  int i = blockIdx.x*256 + threadIdx.x;
  if (i >= nd*LSEQ) return;
  int dz = i >> 14; int dj = (d_base+dz)*2 + j;
  const float* r = zx + (size_t)i*DPROJ + 640;
  #pragma unroll
  for (int h = 0; h < 4; ++h)
    dtb[(size_t)i*4 + h] = softplus_f(r[h] + dt_bias[dj*4 + h]);
}

// ---------------- within-chunk cumulative log-decay (wave scan) ----------------
__global__ __launch_bounds__(256) void k_cum(const float* __restrict__ dtb, const float* __restrict__ A_log,
                                             float* __restrict__ llog, int d_base, int j){
  int blk = blockIdx.x;
  int dz = blk >> 8, c = blk & 255;
  int h = threadIdx.x >> 6, t = threadIdx.x & 63;
  int dj = (d_base+dz)*2 + j;
  float A = -__expf(A_log[dj*4 + h]);
  size_t ro = ((size_t)dz*LSEQ + c*64 + t)*NH + h;
  float v = dtb[ro] * A;
  #pragma unroll
  for (int o = 1; o < 64; o <<= 1){
    float pv = __shfl_up(v, o);
    if (t >= o) v += pv;
  }
  llog[ro] = v;
}

// ---------------- chunk kernel 1: G, intra-chunk Y1 (+D*xs), summaries S ----------------
__global__ __launch_bounds__(256) void k_chunk1(const float* __restrict__ xact, const float* __restrict__ dtb,
                                                const float* __restrict__ llog, const float* __restrict__ Dskip,
                                                float* __restrict__ E, float* __restrict__ zx,
                                                int d_base, int j){
  __shared__ float BsT[64*PAD];  // [n][s]
  __shared__ float CW [64*PAD];  // C^T [n][t], then reused as W1
  __shared__ float Gs [64*PAD];  // [t][s]
  __shared__ float Xs [64*PAD];  // [s][p]
  __shared__ float Lh[64], dts[64];
  int c = blockIdx.x, dz = blockIdx.y, tid = threadIdx.x;
  int dj = (d_base+dz)*2 + j;
  const float* xa = xact + ((size_t)dz*LSEQ + c*64)*CONVD;
  for (int e = tid; e < 4096; e += 256){
    int t = e >> 6, n = e & 63;
    BsT[n*PAD + t] = xa[(size_t)t*CONVD + 256 + n];
    CW [n*PAD + t] = xa[(size_t)t*CONVD + 320 + n];
  }
  __syncthreads();
  int m0 = (tid>>4)*4, n0 = (tid&15)*4;
  { // G[t][s] = sum_n C[t][n]*B[s][n]
    float acc[4][4] = {};
    mac16(CW, BsT, m0, n0, acc);
    #pragma unroll
    for (int r = 0; r < 4; ++r)
      #pragma unroll
      for (int cc = 0; cc < 4; ++cc)
        Gs[(m0+r)*PAD + n0+cc] = acc[r][cc];
  }
  __syncthreads();
  for (int h = 0; h < NH; ++h){
    if (tid < 64){
      size_t ro = ((size_t)dz*LSEQ + c*64 + tid)*NH + h;
      dts[tid] = dtb[ro];
      Lh[tid]  = llog[ro];
    }
    for (int e = tid; e < 4096; e += 256){
      int t = e >> 6, p = e & 63;
      Xs[t*PAD + p] = xa[(size_t)t*CONVD + h*64 + p];
    }
    __syncthreads();
    float Lend = Lh[63];
    // W1[s][n] = B[s][n]*exp(Lend-L_s)*dt_s
    for (int e = tid; e < 4096; e += 256){
      int s = e >> 6, n = e & 63;
      CW[s*PAD + n] = BsT[n*PAD + s] * __expf(Lend - Lh[s]) * dts[s];
    }
    __syncthreads();
    { // S[n][p] = sum_s W1[s][n]*X[s][p]  -> E[dz][c][h][n][p]
      float acc[4][4] = {};
      mac16(CW, Xs, m0, n0, acc);
      float* Ep = E + ((size_t)(dz*NCHUNK + c)*NH + h)*DSTATE*HD;
      #pragma unroll
      for (int r = 0; r < 4; ++r)
        #pragma unroll
        for (int cc = 0; cc < 4; ++cc)
          Ep[(size_t)(m0+r)*HD + n0+cc] = acc[r][cc];
    }
    __syncthreads();
    // W1[s][t] = (s<=t) ? G[t][s]*exp(L_t-L_s)*dt_s : 0   (transposed for mac16)
    for (int e = tid; e < 4096; e += 256){
      int t = e >> 6, s = e & 63;
      CW[s*PAD + t] = (s <= t) ? Gs[t*PAD + s] * __expf(Lh[t] - Lh[s]) * dts[s] : 0.f;
    }
    __syncthreads();
    { // Y1[t][p] = sum_s GhT[s][t]*X[s][p]; write y (+ D*xs) into zx cols 256..511
      float acc[4][4] = {};
      mac16(CW, Xs, m0, n0, acc);
      float dsk = Dskip[dj*NH + h];
      float* yr = zx + ((size_t)dz*LSEQ + c*64)*DPROJ + 256 + h*64;
      #pragma unroll
      for (int r = 0; r < 4; ++r)
        #pragma unroll
        for (int cc = 0; cc < 4; ++cc)
          yr[(size_t)(m0+r)*DPROJ + n0+cc] = acc[r][cc] + dsk * Xs[(m0+r)*PAD + n0+cc];
    }
    __syncthreads();
  }
}

// ---------------- sequential carry over chunks (in-place summaries -> h_init) ----------------
__global__ __launch_bounds__(256) void k_seq(float* __restrict__ E, const float* __restrict__ llog, int nd){
  int i = blockIdx.x*256 + threadIdx.x;
  if (i >= nd*16384) return;
  int dz = i >> 14;
  int h = (i >> 12) & 3;
  int np = i & 4095;
  const size_t stride = (size_t)NH*DSTATE*HD;   // 16384 floats per chunk
  size_t base = (size_t)dz*NCHUNK*stride + (size_t)h*DSTATE*HD + np;
  size_t lb = ((size_t)dz*LSEQ + 63)*NH + h;
  float carry = 0.f;
  float nE = E[base];
  float nP = __expf(llog[lb]);
  for (int c = 0; c < NCHUNK; ++c){
    float e = nE, pt = nP;
    if (c + 1 < NCHUNK){
      nE = E[base + (size_t)(c+1)*stride];
      nP = __expf(llog[lb + (size_t)(c+1)*(64*NH)]);
    }
    E[base + (size_t)c*stride] = carry;
    carry = fmaf(pt, carry, e);
  }
}

// ---------------- chunk kernel 2: Y2 = exp(L_t) * (C @ h_init) added to y ----------------
__global__ __launch_bounds__(256) void k_chunk2(const float* __restrict__ xact, const float* __restrict__ llog,
                                                const float* __restrict__ E, float* __restrict__ zx,
                                                int d_base, int j){
  __shared__ float CsT[64*PAD];  // [n][t]
  __shared__ float Hs [64*PAD];  // [n][p]
  __shared__ float Lh[64];
  int c = blockIdx.x, dz = blockIdx.y, tid = threadIdx.x;
  const float* xa = xact + ((size_t)dz*LSEQ + c*64)*CONVD;
  for (int e = tid; e < 4096; e += 256){
    int t = e >> 6, n = e & 63;
    CsT[n*PAD + t] = xa[(size_t)t*CONVD + 320 + n];
  }
  int m0 = (tid>>4)*4, n0 = (tid&15)*4;
  for (int h = 0; h < NH; ++h){
    if (tid < 64) Lh[tid] = llog[((size_t)dz*LSEQ + c*64 + tid)*NH + h];
    const float* Ep = E + ((size_t)(dz*NCHUNK + c)*NH + h)*DSTATE*HD;
    for (int e = tid; e < 4096; e += 256){
      int n = e >> 6, p = e & 63;
      Hs[n*PAD + p] = Ep[(size_t)n*HD + p];
    }
    __syncthreads();
    float acc[4][4] = {};
    mac16(CsT, Hs, m0, n0, acc);
    float* yr = zx + ((size_t)dz*LSEQ + c*64)*DPROJ + 256 + h*64;
    #pragma unroll
    for (int r = 0; r < 4; ++r){
      float sc = __expf(Lh[m0+r]);
      #pragma unroll
      for (int cc = 0; cc < 4; ++cc)
        yr[(size_t)(m0+r)*DPROJ + n0+cc] += sc * acc[r][cc];
    }
    __syncthreads();
  }
}

// ---------------- gated RMSNorm (in-place on y) ----------------
__global__ __launch_bounds__(256) void k_gate(float* __restrict__ zx, const float* __restrict__ norm_w,
                                              int d_base, int j, int nd){
  int gt = blockIdx.x*256 + threadIdx.x;
  int wid = gt >> 6, lane = gt & 63;
  if (wid >= nd*LSEQ) return;
  int dz = wid >> 14; int dj = (d_base+dz)*2 + j;
  float* row = zx + (size_t)wid*DPROJ;
  float4 z4 = ((const float4*)row)[lane];
  float4 y4 = ((const float4*)(row + 256))[lane];
  float g0 = y4.x * silu_f(z4.x);
  float g1 = y4.y * silu_f(z4.y);
  float g2 = y4.z * silu_f(z4.z);
  float g3 = y4.w * silu_f(z4.w);
  float ss = g0*g0 + g1*g1 + g2*g2 + g3*g3;
  #pragma unroll
  for (int o = 32; o; o >>= 1) ss += __shfl_xor(ss, o);
  float rr = rsqrtf(ss * (1.f/256.f) + 1e-5f);
  float4 nw = ((const float4*)(norm_w + (size_t)dj*DI))[lane];
  float4 o4 = { g0*rr*nw.x, g1*rr*nw.y, g2*rr*nw.z, g3*rr*nw.w };
  ((float4*)(row + 256))[lane] = o4;
}

// ---------------- out_proj: yn[L,256] @ out_w[128,256]^T, += into x ----------------
__global__ __launch_bounds__(256) void k_outproj(const float* __restrict__ zx, const float* __restrict__ out_w,
                                                 float* __restrict__ x, int d_base, int j){
  __shared__ float As[64*PAD], Ws[64*PAD];
  int tid = threadIdx.x, mt = blockIdx.x, nt = blockIdx.y, dz = blockIdx.z;
  const float* A = zx + ((size_t)dz*LSEQ + mt*64)*DPROJ + 256;
  const float* W = out_w + (size_t)((d_base+dz)*2 + j)*DM*DI + (size_t)nt*64*DI;
  float acc[4][4] = {};
  for (int kt = 0; kt < DI; kt += 64){
    stageT(A + kt, DPROJ, 64, As, tid);
    stageT(W + kt, DI, 64, Ws, tid);
    __syncthreads();
    mac16(As, Ws, (tid>>4)*4, (tid&15)*4, acc);
    __syncthreads();
  }
  int m0 = (tid>>4)*4, n0 = (tid&15)*4;
  float* xr = x + ((size_t)dz*LSEQ + mt*64 + m0)*DM + nt*64 + n0;
  #pragma unroll
  for (int r = 0; r < 4; ++r)
    #pragma unroll
    for (int c = 0; c < 4; ++c)
      xr[(size_t)r*DM + c] += acc[r][c];
}

// ---------------- fuse GEMM + bias + exact gelu ----------------
__global__ __launch_bounds__(256) void k_fuse(const float* __restrict__ fh, const float* __restrict__ fw,
                                              const float* __restrict__ fb, float* __restrict__ out){
  __shared__ float As[64*PAD], Ws[64*PAD];
  int tid = threadIdx.x, mt = blockIdx.x, nt = blockIdx.y;
  const float* A = fh + (size_t)mt*64*768;
  const float* W = fw + (size_t)nt*64*768;
  float acc[4][4] = {};
  for (int kt = 0; kt < 768; kt += 64){
    stageT(A + kt, 768, 64, As, tid);
    stageT(W + kt, 768, 64, Ws, tid);
    __syncthreads();
    mac16(As, Ws, (tid>>4)*4, (tid&15)*4, acc);
    __syncthreads();
  }
  int m0 = (tid>>4)*4, n0 = (tid&15)*4;
  #pragma unroll
  for (int r = 0; r < 4; ++r)
    #pragma unroll
    for (int c = 0; c < 4; ++c){
      int col = nt*64 + n0 + c;
      float v = acc[r][c] + fb[col];
      float g = 0.5f * v * (1.f + erff(v * 0.70710678118654752f));
      out[(size_t)(mt*64 + m0 + r)*DM + col] = g;
    }
}

extern "C" void kernel_launch(void* const* d_in, const int* in_sizes, int n_in,
                              void* d_out, int out_size, void* d_ws, size_t ws_size,
                              hipStream_t stream){
  (void)in_sizes; (void)n_in; (void)out_size;
  const float* vectors  = (const float*)d_in[0];
  const int*   coords   = (const int*)d_in[1];
  const float* ln_w     = (const float*)d_in[2];
  const float* ln_b     = (const float*)d_in[3];
  const float* in_w     = (const float*)d_in[4];
  const float* conv_w   = (const float*)d_in[5];
  const float* conv_b   = (const float*)d_in[6];
  const float* dt_bias  = (const float*)d_in[7];
  const float* A_log    = (const float*)d_in[8];
  const float* D_skip   = (const float*)d_in[9];
  const float* norm_w   = (const float*)d_in[10];
  const float* out_w    = (const float*)d_in[11];
  const float* fuse_lw  = (const float*)d_in[12];
  const float* fuse_lb  = (const float*)d_in[13];
  const float* fuse_w   = (const float*)d_in[14];
  const float* fuse_b   = (const float*)d_in[15];
  float* out = (float*)d_out;

  char* p = (char*)d_ws;
  auto carve = [&](size_t bytes)->char*{
    char* r = p; p += (bytes + 255) & ~(size_t)255; return r;
  };
  int* idxb = (int*)carve((size_t)NDIR*LSEQ*4);
  int* invb = (int*)carve((size_t)NDIR*LSEQ*4);
  unsigned long long* skey  = (unsigned long long*)carve((size_t)NDIR*LSEQ*8);
  unsigned long long* skey2 = (unsigned long long*)carve((size_t)NDIR*LSEQ*8);
  int* starts = (int*)carve((size_t)NDIR*1025*4);
  int* cursor = (int*)carve((size_t)NDIR*1024*4);
  float* multi = (float*)carve((size_t)LSEQ*768*4);
  float* fuseh = (float*)carve((size_t)LSEQ*768*4);

  size_t fixed = (size_t)(p - (char*)d_ws);
  auto need = [&](int nd)->size_t{
    size_t s = 0; auto a = [&](size_t b){ s += (b + 255) & ~(size_t)255; };
    a((size_t)nd*LSEQ*DM*4);      // x
    a((size_t)nd*LSEQ*DM*4);      // u
    a((size_t)nd*LSEQ*DPROJ*4);   // zx
    a((size_t)nd*LSEQ*CONVD*4);   // xact
    a((size_t)nd*LSEQ*NH*4);      // dt
    a((size_t)nd*LSEQ*NH*4);      // llog
    a((size_t)nd*NCHUNK*NH*DSTATE*HD*4); // E
    return s;
  };
  int nd = 6;
  if (fixed + need(6) > ws_size) nd = 1;
  if (fixed + need(nd) > ws_size) return;  // insufficient workspace: no-op

  float* xbuf = (float*)carve((size_t)nd*LSEQ*DM*4);
  float* ubuf = (float*)carve((size_t)nd*LSEQ*DM*4);
  float* zx   = (float*)carve((size_t)nd*LSEQ*DPROJ*4);
  float* xact = (float*)carve((size_t)nd*LSEQ*CONVD*4);
  float* dtb  = (float*)carve((size_t)nd*LSEQ*NH*4);
  float* llog = (float*)carve((size_t)nd*LSEQ*NH*4);
  float* Ebuf = (float*)carve((size_t)nd*NCHUNK*NH*DSTATE*HD*4);

  hipMemsetAsync(cursor, 0, (size_t)NDIR*1024*4, stream);
  k_sort1       <<<(NDIR*LSEQ + 255)/256, 256, 0, stream>>>(coords, skey, cursor);
  k_sort_scan   <<<NDIR, 1024, 0, stream>>>(cursor, starts);
  k_sort_scatter<<<(NDIR*LSEQ + 255)/256, 256, 0, stream>>>(skey, skey2, cursor);
  k_sort_rank   <<<(NDIR*LSEQ + 255)/256, 256, 0, stream>>>(skey2, starts, idxb, invb);

  for (int d_base = 0; d_base < NDIR; d_base += nd){
    k_gather<<<nd*2048, 256, 0, stream>>>(vectors, idxb, xbuf, d_base, nd);
    for (int j = 0; j < 2; ++j){
      k_ln128 <<<nd*LSEQ/4, 256, 0, stream>>>(xbuf, ln_w, ln_b, ubuf, d_base, j, nd);
      k_inproj<<<dim3(LSEQ/64, 11, nd), 256, 0, stream>>>(ubuf, in_w, zx, d_base, j);
      k_conv  <<<dim3(nd, LSEQ/64, 3), 256, 0, stream>>>(zx, conv_w, conv_b, xact, d_base, j);
      k_dt    <<<nd*64, 256, 0, stream>>>(zx, dt_bias, dtb, d_base, j, nd);
      k_cum   <<<nd*NCHUNK, 256, 0, stream>>>(dtb, A_log, llog, d_base, j);
      k_chunk1<<<dim3(NCHUNK, nd), 256, 0, stream>>>(xact, dtb, llog, D_skip, Ebuf, zx, d_base, j);
      k_seq   <<<nd*64, 256, 0, stream>>>(Ebuf, llog, nd);
      k_chunk2<<<dim3(NCHUNK, nd), 256, 0, stream>>>(xact, llog, Ebuf, zx, d_base, j);
      k_gate  <<<nd*LSEQ/4, 256, 0, stream>>>(zx, norm_w, d_base, j, nd);
      k_outproj<<<dim3(LSEQ/64, 2, nd), 256, 0, stream>>>(zx, out_w, xbuf, d_base, j);
    }
    k_scatter<<<nd*2048, 256, 0, stream>>>(xbuf, idxb, multi, d_base, nd);
  }
  k_ln768<<<LSEQ/4, 256, 0, stream>>>(multi, fuse_lw, fuse_lb, fuseh);
  k_fuse <<<dim3(LSEQ/64, 2), 256, 0, stream>>>(fuseh, fuse_w, fuse_b, out);
}

// Round 2
// 1744.984 us; speedup vs baseline: 1.6777x; 1.6777x over previous
//
#include <hip/hip_runtime.h>
#include <math.h>

#define LSEQ   16384
#define DM     128
#define DI     256
#define DSTATE 64
#define NH     4
#define HD     64
#define CONVD  384
#define DPROJ  644
#define NDIR   6
#define NCHUNK 256      // LSEQ/64

typedef unsigned short u16;
typedef __attribute__((ext_vector_type(8))) __bf16 bf16x8;
typedef __attribute__((ext_vector_type(4))) float f32x4;

union U8 { uint4 v; u16 h[8]; };

__device__ __constant__ int ORD[6][3] = {{0,1,2},{0,2,1},{1,0,2},{1,2,0},{2,0,1},{2,1,0}};

__device__ __forceinline__ float softplus_f(float x){
  float ax = fabsf(x);
  return fmaxf(x, 0.f) + log1pf(__expf(-ax));
}
__device__ __forceinline__ float silu_f(float x){
  return x / (1.f + __expf(-x));
}
__device__ __forceinline__ u16 f2b(float f){
  unsigned u = __float_as_uint(f);
  unsigned r = (u + 0x7fffu + ((u >> 16) & 1u)) >> 16;
  return (u16)r;
}
__device__ __forceinline__ float b2f(u16 h){
  return __uint_as_float(((unsigned)h) << 16);
}
// XOR swizzle for [rows][128B] bf16 LDS tiles: conflict-free ds_read_b128 (T2)
__device__ __forceinline__ int SWZ(int r, int cb){
  return r*128 + (cb ^ ((r & 7) << 4));
}

// ---------------- weight convert to bf16 ----------------
#define NW0 (12*768*128)
#define NW1 (12*128*256)
#define NW2 (128*768)
__global__ __launch_bounds__(256) void k_cvt(const float* __restrict__ in_w,
                                             const float* __restrict__ out_w,
                                             const float* __restrict__ fuse_w,
                                             u16* __restrict__ wi, u16* __restrict__ wo,
                                             u16* __restrict__ wf){
  int i = blockIdx.x*256 + threadIdx.x;
  if (i < NW0){
    int dj = i / (768*128), rem = i % (768*128), r = rem >> 7, c = rem & 127;
    float v = (r < DPROJ) ? in_w[((size_t)dj*DPROJ + r)*128 + c] : 0.f;
    wi[i] = f2b(v);
  } else if (i < NW0 + NW1){
    int k = i - NW0;
    wo[k] = f2b(out_w[k]);
  } else if (i < NW0 + NW1 + NW2){
    int k = i - NW0 - NW1;
    wf[k] = f2b(fuse_w[k]);
  }
}

// ---------------- sort: bucket by primary coord, O(m^2) in-bucket rank ----------------
__global__ __launch_bounds__(256) void k_sort1(const int* __restrict__ coords,
                                               unsigned long long* __restrict__ skey,
                                               int* __restrict__ cursor){
  int i = blockIdx.x*256 + threadIdx.x;
  if (i >= NDIR*LSEQ) return;
  int d = i >> 14, t = i & 16383;
  unsigned k = ((unsigned)coords[t*4 + ORD[d][0]] << 20)
             | ((unsigned)coords[t*4 + ORD[d][1]] << 10)
             |  (unsigned)coords[t*4 + ORD[d][2]];
  skey[i] = ((unsigned long long)k << 14) | (unsigned long long)t;
  atomicAdd(&cursor[(d << 10) + (k >> 20)], 1);
}

__global__ void k_sort_scan(int* __restrict__ cursor, int* __restrict__ starts){
  __shared__ int sh[1024];
  int d = blockIdx.x, t = threadIdx.x;
  int v = cursor[d*1024 + t];
  sh[t] = v; __syncthreads();
  for (int off = 1; off < 1024; off <<= 1){
    int a = (t >= off) ? sh[t-off] : 0;
    __syncthreads();
    sh[t] += a;
    __syncthreads();
  }
  int incl = sh[t], excl = incl - v;
  starts[d*1025 + t] = excl;
  cursor[d*1024 + t] = excl;
  if (t == 1023) starts[d*1025 + 1024] = incl;
}

__global__ __launch_bounds__(256) void k_sort_scatter(const unsigned long long* __restrict__ skey,
                                                      unsigned long long* __restrict__ skey2,
                                                      int* __restrict__ cursor){
  int i = blockIdx.x*256 + threadIdx.x;
  if (i >= NDIR*LSEQ) return;
  int d = i >> 14;
  unsigned long long v = skey[i];
  int b = (int)(v >> 34);
  int pos = atomicAdd(&cursor[(d << 10) + b], 1);
  skey2[(size_t)d*LSEQ + pos] = v;
}

__global__ __launch_bounds__(256) void k_sort_rank(const unsigned long long* __restrict__ skey2,
                                                   const int* __restrict__ starts,
                                                   int* __restrict__ idx, int* __restrict__ inv){
  int i = blockIdx.x*256 + threadIdx.x;
  if (i >= NDIR*LSEQ) return;
  int d = i >> 14;
  unsigned long long v = skey2[i];
  int b = (int)(v >> 34);
  int s = starts[d*1025 + b], e = starts[d*1025 + b + 1];
  int r = s;
  for (int q = s; q < e; ++q) r += (skey2[(size_t)d*LSEQ + q] < v);
  int orig = (int)(v & 16383ULL);
  idx[(size_t)d*LSEQ + r] = orig;
  inv[(size_t)d*LSEQ + orig] = r;
}

// ---------------- gather / scatter ----------------
__global__ __launch_bounds__(256) void k_gather(const float* __restrict__ vec, const int* __restrict__ idx,
                                                float* __restrict__ x, int d_base, int nd){
  int i = blockIdx.x*256 + threadIdx.x;
  if (i >= nd*LSEQ*32) return;
  int c4 = i & 31, r = (i >> 5) & 16383, dz = i >> 19;
  int src = idx[(size_t)(d_base+dz)*LSEQ + r];
  ((float4*)x)[((size_t)dz*LSEQ + r)*32 + c4] = ((const float4*)vec)[(size_t)src*32 + c4];
}

__global__ __launch_bounds__(256) void k_scatter(const float* __restrict__ x, const int* __restrict__ idx,
                                                 float* __restrict__ multi, int d_base, int nd){
  int i = blockIdx.x*256 + threadIdx.x;
  if (i >= nd*LSEQ*32) return;
  int c4 = i & 31, r = (i >> 5) & 16383, dz = i >> 19;
  int orig = idx[(size_t)(d_base+dz)*LSEQ + r];
  ((float4*)multi)[(size_t)orig*192 + (d_base+dz)*32 + c4] =
      ((const float4*)x)[((size_t)dz*LSEQ + r)*32 + c4];
}

// ---------------- layernorms ----------------
__global__ __launch_bounds__(256) void k_ln128(const float* __restrict__ x, const float* __restrict__ w,
                                               const float* __restrict__ b, u16* __restrict__ u,
                                               int d_base, int j, int nd){
  int gt = blockIdx.x*256 + threadIdx.x;
  int wid = gt >> 6, lane = gt & 63;
  if (wid >= nd*LSEQ) return;
  int dz = wid >> 14;
  int dj = (d_base+dz)*2 + j;
  float2 v = ((const float2*)(x + (size_t)wid*DM))[lane];
  float s = v.x + v.y, ss = v.x*v.x + v.y*v.y;
  #pragma unroll
  for (int o = 32; o; o >>= 1){ s += __shfl_xor(s,o); ss += __shfl_xor(ss,o); }
  float mu = s * (1.f/128.f);
  float var = ss * (1.f/128.f) - mu*mu;
  float inv = rsqrtf(var + 1e-5f);
  float2 wv = ((const float2*)(w + (size_t)dj*DM))[lane];
  float2 bv = ((const float2*)(b + (size_t)dj*DM))[lane];
  unsigned pack = (unsigned)f2b((v.x - mu)*inv*wv.x + bv.x)
                | ((unsigned)f2b((v.y - mu)*inv*wv.y + bv.y) << 16);
  *(unsigned*)(u + (size_t)wid*DM + lane*2) = pack;
}

__global__ __launch_bounds__(256) void k_ln768(const float* __restrict__ m, const float* __restrict__ w,
                                               const float* __restrict__ b, u16* __restrict__ o){
  int gt = blockIdx.x*256 + threadIdx.x;
  int wid = gt >> 6, lane = gt & 63;
  if (wid >= LSEQ) return;
  const float4* row = (const float4*)(m + (size_t)wid*768);
  float4 v0 = row[lane], v1 = row[lane+64], v2 = row[lane+128];
  float s  = v0.x+v0.y+v0.z+v0.w + v1.x+v1.y+v1.z+v1.w + v2.x+v2.y+v2.z+v2.w;
  float ss = v0.x*v0.x+v0.y*v0.y+v0.z*v0.z+v0.w*v0.w
           + v1.x*v1.x+v1.y*v1.y+v1.z*v1.z+v1.w*v1.w
           + v2.x*v2.x+v2.y*v2.y+v2.z*v2.z+v2.w*v2.w;
  #pragma unroll
  for (int off = 32; off; off >>= 1){ s += __shfl_xor(s,off); ss += __shfl_xor(ss,off); }
  float mu = s * (1.f/768.f);
  float var = ss * (1.f/768.f) - mu*mu;
  float inv = rsqrtf(var + 1e-5f);
  const float4* w4 = (const float4*)w;
  const float4* b4 = (const float4*)b;
  #pragma unroll
  for (int kk = 0; kk < 3; ++kk){
    float4 v = (kk==0)?v0:((kk==1)?v1:v2);
    float4 W = w4[lane + kk*64], B = b4[lane + kk*64];
    uint2 pk;
    pk.x = (unsigned)f2b((v.x-mu)*inv*W.x + B.x) | ((unsigned)f2b((v.y-mu)*inv*W.y + B.y) << 16);
    pk.y = (unsigned)f2b((v.z-mu)*inv*W.z + B.z) | ((unsigned)f2b((v.w-mu)*inv*W.w + B.w) << 16);
    *(uint2*)(o + (size_t)wid*768 + (lane + kk*64)*4) = pk;
  }
}

// ---------------- shared 128x128 bf16 MFMA GEMM core (A[M,K], B[N,K], both K-contiguous) ----------------
__device__ __forceinline__ void gemm128_core(const u16* __restrict__ Ag, int lda,
                                             const u16* __restrict__ Bg, int ldb,
                                             int nkt, u16* As, u16* Bs, int tid,
                                             f32x4 acc[4][4]){
  int l = tid & 63, w = tid >> 6, wr = w >> 1, wc = w & 1;
  for (int kt = 0; kt < nkt; ++kt){
    #pragma unroll
    for (int it = 0; it < 4; ++it){
      int idx = it*256 + tid, r = idx >> 3, slot = idx & 7;
      uint4 va = *(const uint4*)(Ag + (size_t)r*lda + kt*64 + slot*8);
      uint4 vb = *(const uint4*)(Bg + (size_t)r*ldb + kt*64 + slot*8);
      *(uint4*)((char*)As + SWZ(r, slot*16)) = va;
      *(uint4*)((char*)Bs + SWZ(r, slot*16)) = vb;
    }
    __syncthreads();
    #pragma unroll
    for (int ks = 0; ks < 64; ks += 32){
      bf16x8 a[4], b[4];
      int cb = (ks + (l >> 4)*8)*2;
      #pragma unroll
      for (int i = 0; i < 4; ++i){
        a[i] = *(bf16x8*)((char*)As + SWZ(wr*64 + i*16 + (l & 15), cb));
        b[i] = *(bf16x8*)((char*)Bs + SWZ(wc*64 + i*16 + (l & 15), cb));
      }
      #pragma unroll
      for (int i = 0; i < 4; ++i)
        #pragma unroll
        for (int jn = 0; jn < 4; ++jn)
          acc[i][jn] = __builtin_amdgcn_mfma_f32_16x16x32_bf16(a[i], b[jn], acc[i][jn], 0, 0, 0);
    }
    __syncthreads();
  }
}

// ---------------- in_proj ----------------
__global__ __launch_bounds__(256) void k_inproj(const u16* __restrict__ u, const u16* __restrict__ wbf,
                                                const float* __restrict__ dt_bias,
                                                u16* __restrict__ zbuf, u16* __restrict__ xbc,
                                                float* __restrict__ dtb, int d_base, int j){
  __shared__ __align__(16) u16 smem[16384];
  int bn = blockIdx.x, mt = blockIdx.y, dz = blockIdx.z, tid = threadIdx.x;
  int dj = (d_base + dz)*2 + j;
  const u16* Ag = u + ((size_t)dz*LSEQ + mt*128)*DM;
  const u16* Bg = wbf + (size_t)dj*768*DM + (size_t)bn*128*DM;
  f32x4 acc[4][4] = {};
  gemm128_core(Ag, DM, Bg, DM, 2, smem, smem + 8192, tid, acc);
  int l = tid & 63, w = tid >> 6, wr = w >> 1, wc = w & 1;
  if (bn < 5){
    #pragma unroll
    for (int i = 0; i < 4; ++i)
      #pragma unroll
      for (int jn = 0; jn < 4; ++jn)
        #pragma unroll
        for (int r = 0; r < 4; ++r){
          int m = wr*64 + i*16 + (l >> 4)*4 + r, n = wc*64 + jn*16 + (l & 15);
          smem[m*128 + n] = f2b(acc[i][jn][r]);
        }
    __syncthreads();
    u16* dst; int ld;
    int co0 = bn*128;
    if (co0 < 256){ dst = zbuf + ((size_t)dz*LSEQ + mt*128)*256 + co0; ld = 256; }
    else         { dst = xbc + ((size_t)dz*LSEQ + mt*128)*384 + (co0 - 256); ld = 384; }
    #pragma unroll
    for (int it = 0; it < 8; ++it){
      int idx = it*256 + tid, r = idx >> 4, slot = idx & 15;
      uint4 v = *(uint4*)(smem + r*128 + slot*8);
      *(uint4*)(dst + (size_t)r*ld + slot*8) = v;
    }
  } else {
    #pragma unroll
    for (int i = 0; i < 4; ++i)
      #pragma unroll
      for (int jn = 0; jn < 4; ++jn)
        #pragma unroll
        for (int r = 0; r < 4; ++r){
          int m = wr*64 + i*16 + (l >> 4)*4 + r, n = wc*64 + jn*16 + (l & 15);
          if (n < 4){
            float v = acc[i][jn][r] + dt_bias[dj*4 + n];
            dtb[((size_t)dz*LSEQ + mt*128 + m)*4 + n] = softplus_f(v);
          }
        }
  }
}

// ---------------- depthwise conv(4) + bias + silu (bf16 in/out) ----------------
__global__ __launch_bounds__(256) void k_conv(const u16* __restrict__ xbc, const float* __restrict__ conv_w,
                                              const float* __restrict__ conv_b, u16* __restrict__ xact,
                                              int d_base, int j){
  __shared__ float tile[67][129];
  __shared__ float wsh[128][4];
  __shared__ float bsh[128];
  int dz = blockIdx.x, lb = blockIdx.y*64, cb = blockIdx.z*128;
  int dj = (d_base+dz)*2 + j;
  const u16* src = xbc + (size_t)dz*LSEQ*CONVD + cb;
  for (int e = threadIdx.x; e < 67*128; e += 256){
    int r = e >> 7, c = e & 127;
    int l = lb - 3 + r;
    tile[r][c] = (l >= 0) ? b2f(src[(size_t)l*CONVD + c]) : 0.f;
  }
  if (threadIdx.x < 128){
    int c = threadIdx.x;
    const float* wp = conv_w + ((size_t)dj*CONVD + cb + c)*4;
    wsh[c][0]=wp[0]; wsh[c][1]=wp[1]; wsh[c][2]=wp[2]; wsh[c][3]=wp[3];
    bsh[c] = conv_b[(size_t)dj*CONVD + cb + c];
  }
  __syncthreads();
  for (int e = threadIdx.x; e < 64*128; e += 256){
    int r = e >> 7, c = e & 127;
    float v = tile[r][c]*wsh[c][0] + tile[r+1][c]*wsh[c][1]
            + tile[r+2][c]*wsh[c][2] + tile[r+3][c]*wsh[c][3] + bsh[c];
    xact[((size_t)dz*LSEQ + lb + r)*CONVD + cb + c] = f2b(silu_f(v));
  }
}

// ---------------- within-chunk cumulative log-decay (wave scan) ----------------
__global__ __launch_bounds__(256) void k_cum(const float* __restrict__ dtb, const float* __restrict__ A_log,
                                             float* __restrict__ llog, int d_base, int j){
  int blk = blockIdx.x;
  int dz = blk >> 8, c = blk & 255;
  int h = threadIdx.x >> 6, t = threadIdx.x & 63;
  int dj = (d_base+dz)*2 + j;
  float A = -__expf(A_log[dj*4 + h]);
  size_t ro = ((size_t)dz*LSEQ + c*64 + t)*NH + h;
  float v = dtb[ro] * A;
  #pragma unroll
  for (int o = 1; o < 64; o <<= 1){
    float pv = __shfl_up(v, o);
    if (t >= o) v += pv;
  }
  llog[ro] = v;
}

// ---------------- chunk kernel 1 (MFMA): G, Y1 (+D*xs), summaries S^T -> E[p][n] ----------------
__global__ __launch_bounds__(256) void k_chunk1(const u16* __restrict__ xact, const float* __restrict__ dtb,
                                                const float* __restrict__ llog, const float* __restrict__ Dskip,
                                                float* __restrict__ E, float* __restrict__ ybuf,
                                                int d_base, int j){
  __shared__ __align__(16) u16 sC[4096], sB[4096], sM[4096], sXt[4096], sBw[4096];
  __shared__ float sL[64], sdt[64];
  int c = blockIdx.x, dz = blockIdx.y, tid = threadIdx.x;
  int dj = (d_base + dz)*2 + j;
  const u16* xa = xact + ((size_t)dz*LSEQ + c*64)*CONVD;
  // stage B (cols 256..319) and C (cols 320..383)
  #pragma unroll
  for (int it = 0; it < 2; ++it){
    int idx = it*256 + tid, r = idx >> 3, slot = idx & 7;
    uint4 vB = *(const uint4*)(xa + (size_t)r*CONVD + 256 + slot*8);
    uint4 vC = *(const uint4*)(xa + (size_t)r*CONVD + 320 + slot*8);
    *(uint4*)((char*)sB + SWZ(r, slot*16)) = vB;
    *(uint4*)((char*)sC + SWZ(r, slot*16)) = vC;
  }
  __syncthreads();
  int l = tid & 63, w = tid >> 6, wr = w >> 1, wc = w & 1;
  int mb = wr*32, nb = wc*32;
  // G[t][s] = sum_n C[t][n] * B[s][n]
  f32x4 g[2][2] = {};
  #pragma unroll
  for (int ks = 0; ks < 64; ks += 32){
    bf16x8 a[2], b[2];
    int cb = (ks + (l >> 4)*8)*2;
    #pragma unroll
    for (int i = 0; i < 2; ++i){
      a[i] = *(bf16x8*)((char*)sC + SWZ(mb + i*16 + (l & 15), cb));
      b[i] = *(bf16x8*)((char*)sB + SWZ(nb + i*16 + (l & 15), cb));
    }
    #pragma unroll
    for (int i = 0; i < 2; ++i)
      #pragma unroll
      for (int jn = 0; jn < 2; ++jn)
        g[i][jn] = __builtin_amdgcn_mfma_f32_16x16x32_bf16(a[i], b[jn], g[i][jn], 0, 0, 0);
  }
  for (int h = 0; h < NH; ++h){
    __syncthreads();
    if (tid < 64){
      size_t ro = ((size_t)dz*LSEQ + c*64 + tid)*NH + h;
      sdt[tid] = dtb[ro];
      sL[tid]  = llog[ro];
    }
    __syncthreads();
    // build M[t][s] = (s<=t) ? G*exp(Lt-Ls)*dt_s : 0  (bf16)
    #pragma unroll
    for (int i = 0; i < 2; ++i)
      #pragma unroll
      for (int jn = 0; jn < 2; ++jn)
        #pragma unroll
        for (int r = 0; r < 4; ++r){
          int t = mb + i*16 + (l >> 4)*4 + r;
          int s = nb + jn*16 + (l & 15);
          float v = (s <= t) ? g[i][jn][r]*__expf(sL[t]-sL[s])*sdt[s] : 0.f;
          *(u16*)((char*)sM + SWZ(t, s*2)) = f2b(v);
        }
    // build Bw[n][s] = B[s][n]*exp(Lend-Ls)*dt_s  and  Xt[p][s] = X[s][p]
    float Lend = sL[63];
    #pragma unroll
    for (int it = 0; it < 2; ++it){
      int idx = it*256 + tid, s = idx >> 3, ng = idx & 7;
      float wgt = __expf(Lend - sL[s]) * sdt[s];
      bf16x8 bv = *(bf16x8*)((char*)sB + SWZ(s, ng*16));
      U8 xv; xv.v = *(const uint4*)(xa + (size_t)s*CONVD + h*64 + ng*8);
      #pragma unroll
      for (int i2 = 0; i2 < 8; ++i2){
        int n = ng*8 + i2;
        *(u16*)((char*)sBw + SWZ(n, s*2)) = f2b((float)bv[i2] * wgt);
        *(u16*)((char*)sXt + SWZ(n, s*2)) = xv.h[i2];
      }
    }
    __syncthreads();
    // Y1[t][p] = M x Xt ; S^T[p][n] = Xt x Bw
    f32x4 y1[2][2] = {}, ss[2][2] = {};
    #pragma unroll
    for (int ks = 0; ks < 64; ks += 32){
      int cb = (ks + (l >> 4)*8)*2;
      bf16x8 am[2], ax[2], bx[2], bw[2];
      #pragma unroll
      for (int i = 0; i < 2; ++i){
        am[i] = *(bf16x8*)((char*)sM  + SWZ(mb + i*16 + (l & 15), cb));
        ax[i] = *(bf16x8*)((char*)sXt + SWZ(mb + i*16 + (l & 15), cb));
        bx[i] = *(bf16x8*)((char*)sXt + SWZ(nb + i*16 + (l & 15), cb));
        bw[i] = *(bf16x8*)((char*)sBw + SWZ(nb + i*16 + (l & 15), cb));
      }
      #pragma unroll
      for (int i = 0; i < 2; ++i)
        #pragma unroll
        for (int jn = 0; jn < 2; ++jn){
          y1[i][jn] = __builtin_amdgcn_mfma_f32_16x16x32_bf16(am[i], bx[jn], y1[i][jn], 0, 0, 0);
          ss[i][jn] = __builtin_amdgcn_mfma_f32_16x16x32_bf16(ax[i], bw[jn], ss[i][jn], 0, 0, 0);
        }
    }
    float dsk = Dskip[dj*NH + h];
    float* yr = ybuf + ((size_t)dz*LSEQ + c*64)*DI + h*64;
    float* Ep = E + (((size_t)(dz*NCHUNK + c)*NH) + h)*4096;
    #pragma unroll
    for (int i = 0; i < 2; ++i)
      #pragma unroll
      for (int jn = 0; jn < 2; ++jn)
        #pragma unroll
        for (int r = 0; r < 4; ++r){
          int m = mb + i*16 + (l >> 4)*4 + r, n = nb + jn*16 + (l & 15);
          float xs = b2f(*(u16*)((char*)sXt + SWZ(n, m*2)));  // X[t=m][p=n]
          yr[(size_t)m*DI + n] = y1[i][jn][r] + dsk * xs;
          Ep[m*64 + n] = ss[i][jn][r];                        // E[p=m][n]
        }
  }
}

// ---------------- sequential carry over chunks (in-place summaries -> h_init) ----------------
__global__ __launch_bounds__(256) void k_seq(float* __restrict__ E, const float* __restrict__ llog, int nd){
  int i = blockIdx.x*256 + threadIdx.x;
  if (i >= nd*16384) return;
  int dz = i >> 14;
  int h = (i >> 12) & 3;
  int np = i & 4095;
  const size_t stride = (size_t)NH*DSTATE*HD;   // 16384 floats per chunk
  size_t base = (size_t)dz*NCHUNK*stride + (size_t)h*DSTATE*HD + np;
  size_t lb = ((size_t)dz*LSEQ + 63)*NH + h;
  float carry = 0.f;
  float nE = E[base];
  float nP = __expf(llog[lb]);
  for (int c = 0; c < NCHUNK; ++c){
    float e = nE, pt = nP;
    if (c + 1 < NCHUNK){
      nE = E[base + (size_t)(c+1)*stride];
      nP = __expf(llog[lb + (size_t)(c+1)*(64*NH)]);
    }
    E[base + (size_t)c*stride] = carry;
    carry = fmaf(pt, carry, e);
  }
}

// ---------------- chunk kernel 2 (MFMA): Y2 = exp(L_t) * (C @ h_init), += into y ----------------
__global__ __launch_bounds__(256) void k_chunk2(const u16* __restrict__ xact, const float* __restrict__ llog,
                                                const float* __restrict__ E, float* __restrict__ ybuf,
                                                int d_base, int j){
  __shared__ __align__(16) u16 sC[4096], sHt[4096];
  __shared__ float sL[64];
  int c = blockIdx.x, dz = blockIdx.y, tid = threadIdx.x;
  const u16* xa = xact + ((size_t)dz*LSEQ + c*64)*CONVD;
  #pragma unroll
  for (int it = 0; it < 2; ++it){
    int idx = it*256 + tid, r = idx >> 3, slot = idx & 7;
    uint4 vC = *(const uint4*)(xa + (size_t)r*CONVD + 320 + slot*8);
    *(uint4*)((char*)sC + SWZ(r, slot*16)) = vC;
  }
  int l = tid & 63, w = tid >> 6, wr = w >> 1, wc = w & 1;
  int mb = wr*32, nb = wc*32;
  for (int h = 0; h < NH; ++h){
    __syncthreads();
    if (tid < 64) sL[tid] = llog[((size_t)dz*LSEQ + c*64 + tid)*NH + h];
    const float* Ep = E + (((size_t)(dz*NCHUNK + c)*NH) + h)*4096;
    #pragma unroll
    for (int it = 0; it < 2; ++it){
      int idx = it*256 + tid, p = idx >> 3, ng = idx & 7;
      const float* er = Ep + (size_t)p*64 + ng*8;
      U8 pk;
      #pragma unroll
      for (int i2 = 0; i2 < 8; ++i2) pk.h[i2] = f2b(er[i2]);
      *(uint4*)((char*)sHt + SWZ(p, ng*16)) = pk.v;
    }
    __syncthreads();
    // Y2[t][p] = sum_n C[t][n] * Ht[p][n]
    f32x4 acc[2][2] = {};
    #pragma unroll
    for (int ks = 0; ks < 64; ks += 32){
      int cb = (ks + (l >> 4)*8)*2;
      bf16x8 a[2], b[2];
      #pragma unroll
      for (int i = 0; i < 2; ++i){
        a[i] = *(bf16x8*)((char*)sC  + SWZ(mb + i*16 + (l & 15), cb));
        b[i] = *(bf16x8*)((char*)sHt + SWZ(nb + i*16 + (l & 15), cb));
      }
      #pragma unroll
      for (int i = 0; i < 2; ++i)
        #pragma unroll
        for (int jn = 0; jn < 2; ++jn)
          acc[i][jn] = __builtin_amdgcn_mfma_f32_16x16x32_bf16(a[i], b[jn], acc[i][jn], 0, 0, 0);
    }
    float* yr = ybuf + ((size_t)dz*LSEQ + c*64)*DI + h*64;
    #pragma unroll
    for (int i = 0; i < 2; ++i)
      #pragma unroll
      for (int jn = 0; jn < 2; ++jn)
        #pragma unroll
        for (int r = 0; r < 4; ++r){
          int m = mb + i*16 + (l >> 4)*4 + r, n = nb + jn*16 + (l & 15);
          yr[(size_t)m*DI + n] += __expf(sL[m]) * acc[i][jn][r];
        }
  }
}

// ---------------- gated RMSNorm: yn = rms(y*silu(z)) * norm_w  (bf16 out) ----------------
__global__ __launch_bounds__(256) void k_gate(const u16* __restrict__ zbuf, const float* __restrict__ ybuf,
                                              const float* __restrict__ norm_w, u16* __restrict__ yn,
                                              int d_base, int j, int nd){
  int gt = blockIdx.x*256 + threadIdx.x;
  int wid = gt >> 6, lane = gt & 63;
  if (wid >= nd*LSEQ) return;
  int dz = wid >> 14; int dj = (d_base+dz)*2 + j;
  uint2 zp = *(const uint2*)(zbuf + (size_t)wid*DI + lane*4);
  float4 y4 = ((const float4*)(ybuf + (size_t)wid*DI))[lane];
  float z0 = b2f((u16)(zp.x & 0xffff)), z1 = b2f((u16)(zp.x >> 16));
  float z2 = b2f((u16)(zp.y & 0xffff)), z3 = b2f((u16)(zp.y >> 16));
  float g0 = y4.x * silu_f(z0);
  float g1 = y4.y * silu_f(z1);
  float g2 = y4.z * silu_f(z2);
  float g3 = y4.w * silu_f(z3);
  float ssum = g0*g0 + g1*g1 + g2*g2 + g3*g3;
  #pragma unroll
  for (int o = 32; o; o >>= 1) ssum += __shfl_xor(ssum, o);
  float rr = rsqrtf(ssum * (1.f/256.f) + 1e-5f);
  float4 nw = ((const float4*)(norm_w + (size_t)dj*DI))[lane];
  uint2 pk;
  pk.x = (unsigned)f2b(g0*rr*nw.x) | ((unsigned)f2b(g1*rr*nw.y) << 16);
  pk.y = (unsigned)f2b(g2*rr*nw.z) | ((unsigned)f2b(g3*rr*nw.w) << 16);
  *(uint2*)(yn + (size_t)wid*DI + lane*4) = pk;
}

// ---------------- out_proj: yn[L,256] @ out_w[128,256]^T, += into x ----------------
__global__ __launch_bounds__(256) void k_outproj(const u16* __restrict__ yn, const u16* __restrict__ wbf,
                                                 float* __restrict__ x, int d_base, int j){
  __shared__ __align__(16) u16 smem[16384];
  int mt = blockIdx.y, dz = blockIdx.z, tid = threadIdx.x;
  int dj = (d_base + dz)*2 + j;
  const u16* Ag = yn + ((size_t)dz*LSEQ + mt*128)*DI;
  const u16* Bg = wbf + (size_t)dj*DM*DI;
  f32x4 acc[4][4] = {};
  gemm128_core(Ag, DI, Bg, DI, 4, smem, smem + 8192, tid, acc);
  int l = tid & 63, w = tid >> 6, wr = w >> 1, wc = w & 1;
  float* xr = x + ((size_t)dz*LSEQ + mt*128)*DM;
  #pragma unroll
  for (int i = 0; i < 4; ++i)
    #pragma unroll
    for (int jn = 0; jn < 4; ++jn)
      #pragma unroll
      for (int r = 0; r < 4; ++r){
        int m = wr*64 + i*16 + (l >> 4)*4 + r, n = wc*64 + jn*16 + (l & 15);
        xr[(size_t)m*DM + n] += acc[i][jn][r];
      }
}

// ---------------- fuse GEMM + bias + exact gelu ----------------
__global__ __launch_bounds__(256) void k_fuse(const u16* __restrict__ fh, const u16* __restrict__ wbf,
                                              const float* __restrict__ fb, float* __restrict__ out){
  __shared__ __align__(16) u16 smem[16384];
  int mt = blockIdx.y, tid = threadIdx.x;
  const u16* Ag = fh + (size_t)mt*128*768;
  f32x4 acc[4][4] = {};
  gemm128_core(Ag, 768, wbf, 768, 12, smem, smem + 8192, tid, acc);
  int l = tid & 63, w = tid >> 6, wr = w >> 1, wc = w & 1;
  #pragma unroll
  for (int i = 0; i < 4; ++i)
    #pragma unroll
    for (int jn = 0; jn < 4; ++jn)
      #pragma unroll
      for (int r = 0; r < 4; ++r){
        int m = wr*64 + i*16 + (l >> 4)*4 + r, n = wc*64 + jn*16 + (l & 15);
        float v = acc[i][jn][r] + fb[n];
        float g = 0.5f * v * (1.f + erff(v * 0.70710678118654752f));
        out[(size_t)(mt*128 + m)*DM + n] = g;
      }
}

extern "C" void kernel_launch(void* const* d_in, const int* in_sizes, int n_in,
                              void* d_out, int out_size, void* d_ws, size_t ws_size,
                              hipStream_t stream){
  (void)in_sizes; (void)n_in; (void)out_size;
  const float* vectors  = (const float*)d_in[0];
  const int*   coords   = (const int*)d_in[1];
  const float* ln_w     = (const float*)d_in[2];
  const float* ln_b     = (const float*)d_in[3];
  const float* in_w     = (const float*)d_in[4];
  const float* conv_w   = (const float*)d_in[5];
  const float* conv_b   = (const float*)d_in[6];
  const float* dt_bias  = (const float*)d_in[7];
  const float* A_log    = (const float*)d_in[8];
  const float* D_skip   = (const float*)d_in[9];
  const float* norm_w   = (const float*)d_in[10];
  const float* out_w    = (const float*)d_in[11];
  const float* fuse_lw  = (const float*)d_in[12];
  const float* fuse_lb  = (const float*)d_in[13];
  const float* fuse_w   = (const float*)d_in[14];
  const float* fuse_b   = (const float*)d_in[15];
  float* out = (float*)d_out;

  char* p = (char*)d_ws;
  auto carve = [&](size_t bytes)->char*{
    char* r = p; p += (bytes + 255) & ~(size_t)255; return r;
  };
  int* idxb = (int*)carve((size_t)NDIR*LSEQ*4);
  int* invb = (int*)carve((size_t)NDIR*LSEQ*4);
  unsigned long long* skey  = (unsigned long long*)carve((size_t)NDIR*LSEQ*8);
  unsigned long long* skey2 = (unsigned long long*)carve((size_t)NDIR*LSEQ*8);
  int* starts = (int*)carve((size_t)NDIR*1025*4);
  int* cursor = (int*)carve((size_t)NDIR*1024*4);
  float* multi = (float*)carve((size_t)LSEQ*768*4);
  u16*  fuseh = (u16*)carve((size_t)LSEQ*768*2);
  u16*  wbf_in   = (u16*)carve((size_t)NW0*2);
  u16*  wbf_out  = (u16*)carve((size_t)NW1*2);
  u16*  wbf_fuse = (u16*)carve((size_t)NW2*2);

  size_t fixed = (size_t)(p - (char*)d_ws);
  auto need = [&](int nd)->size_t{
    size_t s = 0; auto a = [&](size_t b){ s += (b + 255) & ~(size_t)255; };
    a((size_t)nd*LSEQ*DM*4);      // xbuf (f32)
    a((size_t)nd*LSEQ*DM*2);      // u (bf16)
    a((size_t)nd*LSEQ*DI*2);      // zbuf (bf16)
    a((size_t)nd*LSEQ*CONVD*2);   // xbc (bf16)
    a((size_t)nd*LSEQ*CONVD*2);   // xact (bf16)
    a((size_t)nd*LSEQ*NH*4);      // dtb
    a((size_t)nd*LSEQ*NH*4);      // llog
    a((size_t)nd*LSEQ*DI*4);      // ybuf (f32)
    a((size_t)nd*LSEQ*DI*2);      // yn (bf16)
    a((size_t)nd*NCHUNK*NH*DSTATE*HD*4); // E (f32)
    return s;
  };
  int nd = 6;
  if (fixed + need(6) > ws_size) nd = 1;
  if (fixed + need(nd) > ws_size) return;  // insufficient workspace: no-op

  float* xbuf = (float*)carve((size_t)nd*LSEQ*DM*4);
  u16*   ubuf = (u16*)carve((size_t)nd*LSEQ*DM*2);
  u16*   zbuf = (u16*)carve((size_t)nd*LSEQ*DI*2);
  u16*   xbc  = (u16*)carve((size_t)nd*LSEQ*CONVD*2);
  u16*   xact = (u16*)carve((size_t)nd*LSEQ*CONVD*2);
  float* dtb  = (float*)carve((size_t)nd*LSEQ*NH*4);
  float* llog = (float*)carve((size_t)nd*LSEQ*NH*4);
  float* ybuf = (float*)carve((size_t)nd*LSEQ*DI*4);
  u16*   yn   = (u16*)carve((size_t)nd*LSEQ*DI*2);
  float* Ebuf = (float*)carve((size_t)nd*NCHUNK*NH*DSTATE*HD*4);

  hipMemsetAsync(cursor, 0, (size_t)NDIR*1024*4, stream);
  k_cvt         <<<(NW0+NW1+NW2)/256, 256, 0, stream>>>(in_w, out_w, fuse_w, wbf_in, wbf_out, wbf_fuse);
  k_sort1       <<<(NDIR*LSEQ + 255)/256, 256, 0, stream>>>(coords, skey, cursor);
  k_sort_scan   <<<NDIR, 1024, 0, stream>>>(cursor, starts);
  k_sort_scatter<<<(NDIR*LSEQ + 255)/256, 256, 0, stream>>>(skey, skey2, cursor);
  k_sort_rank   <<<(NDIR*LSEQ + 255)/256, 256, 0, stream>>>(skey2, starts, idxb, invb);

  for (int d_base = 0; d_base < NDIR; d_base += nd){
    k_gather<<<nd*2048, 256, 0, stream>>>(vectors, idxb, xbuf, d_base, nd);
    for (int j = 0; j < 2; ++j){
      k_ln128 <<<nd*LSEQ/4, 256, 0, stream>>>(xbuf, ln_w, ln_b, ubuf, d_base, j, nd);
      k_inproj<<<dim3(6, LSEQ/128, nd), 256, 0, stream>>>(ubuf, wbf_in, dt_bias, zbuf, xbc, dtb, d_base, j);
      k_conv  <<<dim3(nd, LSEQ/64, 3), 256, 0, stream>>>(xbc, conv_w, conv_b, xact, d_base, j);
      k_cum   <<<nd*NCHUNK, 256, 0, stream>>>(dtb, A_log, llog, d_base, j);
      k_chunk1<<<dim3(NCHUNK, nd), 256, 0, stream>>>(xact, dtb, llog, D_skip, Ebuf, ybuf, d_base, j);
      k_seq   <<<nd*64, 256, 0, stream>>>(Ebuf, llog, nd);
      k_chunk2<<<dim3(NCHUNK, nd), 256, 0, stream>>>(xact, llog, Ebuf, ybuf, d_base, j);
      k_gate  <<<nd*LSEQ/4, 256, 0, stream>>>(zbuf, ybuf, norm_w, yn, d_base, j, nd);
      k_outproj<<<dim3(1, LSEQ/128, nd), 256, 0, stream>>>(yn, wbf_out, xbuf, d_base, j);
    }
    k_scatter<<<nd*2048, 256, 0, stream>>>(xbuf, idxb, multi, d_base, nd);
  }
  k_ln768<<<LSEQ/4, 256, 0, stream>>>(multi, fuse_lw, fuse_lb, fuseh);
  k_fuse <<<dim3(1, LSEQ/128), 256, 0, stream>>>(fuseh, wbf_fuse, fuse_b, out);
}